// Round 5
// baseline (2854.945 us; speedup 1.0000x reference)
//
#include <hip/hip_runtime.h>
#include <hip/hip_bf16.h>

// Problem constants
#define B_ 64
#define T_ 8192
#define D_ 128
#define H1_ 128
#define H2_ 64
#define K_ 9
#define CS_ 64        // backtrace chunk size
#define NC_ 128       // number of backtrace chunks

// ---------------------------------------------------------------------------
// Kernel 1: fused MLP -> emissions (B*T, 9), fp32 OUTPUT with each layer's
// dot product accumulated in fp64 (exact), rounded to fp32, bias added in
// fp32, relu in fp32 — mimicking the reference fp32 pipeline with a
// correctly-rounded gemm. Intermediates h1/h2 stored as fp32 (as ref does).
// Block: 256 threads = 4 waves; each wave owns 8 tokens per group; 8 groups.
// LDS: W1 64KB + W2 32KB + x 16KB + h1 16KB = 128KB.
// ---------------------------------------------------------------------------
__global__ __launch_bounds__(256) void mlp_kernel(
    const float* __restrict__ x, const float* __restrict__ W1, const float* __restrict__ b1,
    const float* __restrict__ W2, const float* __restrict__ b2,
    const float* __restrict__ W3, const float* __restrict__ b3,
    float* __restrict__ em) {
  __shared__ __align__(16) float sW1[128 * 128];   // row-major [k][j]
  __shared__ __align__(16) float sW2[128 * 64];    // row-major [k][j2]
  __shared__ __align__(16) float sX[4][1024];      // per-wave x [8][128]; reused as h2 [8][68]
  __shared__ __align__(16) float sH1[4][1024];     // per-wave h1 [8][128]

  const int tid = threadIdx.x;
  {
    float4* d1 = (float4*)sW1;
    const float4* g1 = (const float4*)W1;
    for (int i = tid; i < 128 * 128 / 4; i += 256) d1[i] = g1[i];
    float4* d2 = (float4*)sW2;
    const float4* g2 = (const float4*)W2;
    for (int i = tid; i < 128 * 64 / 4; i += 256) d2[i] = g2[i];
  }
  __syncthreads();

  const int wave = tid >> 6;
  const int lane = tid & 63;
  float* sx = sX[wave];
  float* sh1 = sH1[wave];
  const long blockTok0 = (long)blockIdx.x * 256;

  const float bj0 = b1[lane], bj1 = b1[64 + lane];
  const float b2v = b2[lane];
  const float b3A = b3[lane & 7];
  const float b3B = b3[8];

  for (int g = 0; g < 8; ++g) {
    const long tok0 = blockTok0 + g * 32 + wave * 8;  // 8 tokens for this wave
    const float4* xg = (const float4*)(x + tok0 * 128);
    float4* sx4 = (float4*)sx;
#pragma unroll
    for (int q = 0; q < 4; ++q) sx4[lane + q * 64] = xg[lane + q * 64];

    // ---- Layer 1: fp64 dot, fp32 round, fp32 +bias, fp32 relu ----
    double acc0[8], acc1[8];
#pragma unroll
    for (int t = 0; t < 8; ++t) { acc0[t] = 0.0; acc1[t] = 0.0; }
    for (int k = 0; k < 128; k += 4) {
      float4 xv[8];
#pragma unroll
      for (int t = 0; t < 8; ++t) xv[t] = *(const float4*)&sx[t * 128 + k];
#pragma unroll
      for (int kk = 0; kk < 4; ++kk) {
        const double w0 = (double)sW1[(k + kk) * 128 + lane];
        const double w1 = (double)sW1[(k + kk) * 128 + 64 + lane];
#pragma unroll
        for (int t = 0; t < 8; ++t) {
          const double xs = (double)((const float*)&xv[t])[kk];
          acc0[t] += xs * w0;
          acc1[t] += xs * w1;
        }
      }
    }
#pragma unroll
    for (int t = 0; t < 8; ++t) {
      sh1[t * 128 + lane] = fmaxf((float)acc0[t] + bj0, 0.f);
      sh1[t * 128 + 64 + lane] = fmaxf((float)acc1[t] + bj1, 0.f);
    }

    // ---- Layer 2: fp64 dot of fp32 h1, fp32 round, +bias, relu ----
    double acc2[8];
#pragma unroll
    for (int t = 0; t < 8; ++t) acc2[t] = 0.0;
    for (int k = 0; k < 128; k += 4) {
      float4 hv[8];
#pragma unroll
      for (int t = 0; t < 8; ++t) hv[t] = *(const float4*)&sh1[t * 128 + k];
#pragma unroll
      for (int kk = 0; kk < 4; ++kk) {
        const double w = (double)sW2[(k + kk) * 64 + lane];
#pragma unroll
        for (int t = 0; t < 8; ++t) acc2[t] += (double)((const float*)&hv[t])[kk] * w;
      }
    }
    float* sh2 = sx;  // x tile dead; reuse. Row stride 68 floats.
#pragma unroll
    for (int t = 0; t < 8; ++t) sh2[t * 68 + lane] = fmaxf((float)acc2[t] + b2v, 0.f);

    // ---- Layer 3: fp64 dot of fp32 h2, fp32 round, fp32 +bias ----
    {
      const int tokA = lane >> 3, j3 = lane & 7;
      double acc3 = 0.0;
      for (int k = 0; k < 64; ++k) acc3 += (double)sh2[tokA * 68 + k] * (double)W3[k * 9 + j3];
      em[(tok0 + tokA) * 9 + j3] = (float)acc3 + b3A;
    }
    {
      const int tokB = lane & 7;
      double acc4 = 0.0;
      for (int k = 0; k < 64; ++k) acc4 += (double)sh2[tokB * 68 + k] * (double)W3[k * 9 + 8];
      if (lane < 8) em[(tok0 + tokB) * 9 + 8] = (float)acc4 + b3B;
    }
  }
}

// ---------------------------------------------------------------------------
// Viterbi forward, EXACT sequential fp32 recursion (bitwise reference
// association): cand_i = (s[i] + tr[i][j]) + e[j] — two fp32 ADDs, no
// contraction possible; value = max (order-free); argmax = first-max via
// descending equality scan. Lane layout: 4 batches per wave in 16-lane
// groups, lane%16 = tag j (j<9 active). Emissions prefetched 8 ahead.
// Backpointers stored as bytes bp[b][t][j].
// ---------------------------------------------------------------------------
#define VSTEP(EV, TSTEP)                                                     \
  {                                                                          \
    const float e_ = (EV);                                                   \
    const float s0_ = __shfl(s, 0, 16);                                      \
    const float s1_ = __shfl(s, 1, 16);                                      \
    const float s2_ = __shfl(s, 2, 16);                                      \
    const float s3_ = __shfl(s, 3, 16);                                      \
    const float s4_ = __shfl(s, 4, 16);                                      \
    const float s5_ = __shfl(s, 5, 16);                                      \
    const float s6_ = __shfl(s, 6, 16);                                      \
    const float s7_ = __shfl(s, 7, 16);                                      \
    const float s8_ = __shfl(s, 8, 16);                                      \
    const float c0_ = (s0_ + tr[0]) + e_;                                    \
    const float c1_ = (s1_ + tr[1]) + e_;                                    \
    const float c2_ = (s2_ + tr[2]) + e_;                                    \
    const float c3_ = (s3_ + tr[3]) + e_;                                    \
    const float c4_ = (s4_ + tr[4]) + e_;                                    \
    const float c5_ = (s5_ + tr[5]) + e_;                                    \
    const float c6_ = (s6_ + tr[6]) + e_;                                    \
    const float c7_ = (s7_ + tr[7]) + e_;                                    \
    const float c8_ = (s8_ + tr[8]) + e_;                                    \
    float mx_ = fmaxf(fmaxf(fmaxf(c0_, c1_), fmaxf(c2_, c3_)),               \
                      fmaxf(fmaxf(c4_, c5_), fmaxf(c6_, c7_)));              \
    mx_ = fmaxf(mx_, c8_);                                                   \
    int bi_ = 8;                                                             \
    if (c7_ == mx_) bi_ = 7;                                                 \
    if (c6_ == mx_) bi_ = 6;                                                 \
    if (c5_ == mx_) bi_ = 5;                                                 \
    if (c4_ == mx_) bi_ = 4;                                                 \
    if (c3_ == mx_) bi_ = 3;                                                 \
    if (c2_ == mx_) bi_ = 2;                                                 \
    if (c1_ == mx_) bi_ = 1;                                                 \
    if (c0_ == mx_) bi_ = 0;                                                 \
    if (act) bpb[(long)(TSTEP) * 9] = (unsigned char)bi_;                    \
    s = mx_;                                                                 \
  }

__global__ __launch_bounds__(64) void vit_seq(
    const float* __restrict__ em, const float* __restrict__ trans,
    const float* __restrict__ start_trans,
    unsigned char* __restrict__ bp, float* __restrict__ Sfin) {
  const int lane = threadIdx.x;
  const int grp = lane >> 4;
  const int j = lane & 15;
  const bool act = (j < 9);
  const int jj = act ? j : 8;      // clamp inactive lanes to a valid column
  const int b = blockIdx.x * 4 + grp;

  float tr[9];
#pragma unroll
  for (int i = 0; i < 9; ++i) tr[i] = trans[i * 9 + jj];
  const float* eb = em + ((long)b * T_) * 9 + jj;
  unsigned char* bpb = bp + ((long)b * T_) * 9 + jj;

  float s = start_trans[jj] + eb[0];  // score0, exact reference association

  float ea[8], en[8];
#pragma unroll
  for (int u = 0; u < 8; ++u) ea[u] = eb[(long)(1 + u) * 9];

  for (int tb = 1; tb <= 8177; tb += 8) {  // 1023 groups: steps 1..8184
#pragma unroll
    for (int u = 0; u < 8; ++u) {
      long t2 = tb + 8 + u;
      if (t2 > 8191) t2 = 8191;
      en[u] = eb[t2 * 9];
    }
#pragma unroll
    for (int u = 0; u < 8; ++u) VSTEP(ea[u], tb + u);
#pragma unroll
    for (int u = 0; u < 8; ++u) ea[u] = en[u];
  }
  // tail: steps 8185..8191 (ea[0..6] hold their emissions)
#pragma unroll
  for (int u = 0; u < 7; ++u) VSTEP(ea[u], 8185 + u);

  if (act) Sfin[b * 9 + j] = s;
}

// ---------------------------------------------------------------------------
// Backtrace a: per-chunk composed backpointer map F_c (end-tag -> start-tag),
// 9 nibbles packed in u64. Pure integer => chunking is exact.
// ---------------------------------------------------------------------------
__global__ void vit_p4a(const unsigned char* __restrict__ bp,
                        unsigned long long* __restrict__ Fws) {
  const int task = blockIdx.x * blockDim.x + threadIdx.x;
  if (task >= B_ * NC_) return;
  const int b = task >> 7, c = task & 127;
  int m[9];
#pragma unroll
  for (int q = 0; q < 9; ++q) m[q] = q;
  const int t0 = c * CS_ + 1;
  const int t1 = min(t0 + CS_, T_);
  const unsigned char* bpb = bp + ((long)b * T_) * 9;
  for (int t = t1 - 1; t >= t0; --t) {
#pragma unroll
    for (int q = 0; q < 9; ++q) m[q] = bpb[(long)t * 9 + m[q]];
  }
  unsigned long long f = 0ull;
#pragma unroll
  for (int q = 0; q < 9; ++q) f |= ((unsigned long long)m[q]) << (4 * q);
  Fws[task] = f;
}

// ---------------------------------------------------------------------------
// Backtrace b: final argmax (first-max, ascending strict >) + scan of F maps
// -> chunk-boundary tags. One block, 64 threads (lane = batch).
// ---------------------------------------------------------------------------
__global__ void vit_p4b(const float* __restrict__ Sfin, const float* __restrict__ end_trans,
                        const unsigned long long* __restrict__ Fws,
                        unsigned char* __restrict__ btags, int* __restrict__ out) {
  __shared__ unsigned long long F[B_ * NC_];
  for (int idx = threadIdx.x; idx < B_ * NC_; idx += 64) F[idx] = Fws[idx];
  __syncthreads();
  const int b = threadIdx.x;
  if (b >= B_) return;
  const float* sf = Sfin + b * 9;
  float best = sf[0] + end_trans[0];
  int bi = 0;
#pragma unroll
  for (int q = 1; q < 9; ++q) {
    const float v = sf[q] + end_trans[q];
    if (v > best) { best = v; bi = q; }
  }
  out[b * T_ + T_ - 1] = bi;
  int tag = bi;
  btags[b * (NC_ + 1) + NC_] = (unsigned char)tag;
  for (int c = NC_ - 1; c >= 0; --c) {
    const unsigned long long f = F[b * NC_ + c];
    tag = (int)((f >> (4 * tag)) & 15ull);
    btags[b * (NC_ + 1) + c] = (unsigned char)tag;
  }
}

// ---------------------------------------------------------------------------
// Backtrace c: re-walk each chunk from its known end-boundary tag, writing
// output tags. Pure integer byte-lookup chain.
// ---------------------------------------------------------------------------
__global__ void vit_p4c(const unsigned char* __restrict__ bp,
                        const unsigned char* __restrict__ btags, int* __restrict__ out) {
  const int task = blockIdx.x * blockDim.x + threadIdx.x;
  if (task >= B_ * NC_) return;
  const int b = task >> 7, c = task & 127;
  int tag = btags[b * (NC_ + 1) + c + 1];
  const int t0 = c * CS_ + 1;
  const int t1 = min(t0 + CS_, T_);
  const unsigned char* bpb = bp + ((long)b * T_) * 9;
  int* ob = out + b * T_;
  for (int t = t1 - 1; t >= t0; --t) {
    tag = bpb[(long)t * 9 + tag];
    ob[t - 1] = tag;
  }
}

// ---------------------------------------------------------------------------
extern "C" void kernel_launch(void* const* d_in, const int* in_sizes, int n_in,
                              void* d_out, int out_size, void* d_ws, size_t ws_size,
                              hipStream_t stream) {
  (void)in_sizes; (void)n_in; (void)out_size; (void)ws_size;
  const float* x = (const float*)d_in[0];
  const float* W1 = (const float*)d_in[1];
  const float* b1 = (const float*)d_in[2];
  const float* W2 = (const float*)d_in[3];
  const float* b2 = (const float*)d_in[4];
  const float* W3 = (const float*)d_in[5];
  const float* b3 = (const float*)d_in[6];
  const float* start_trans = (const float*)d_in[7];
  const float* end_trans = (const float*)d_in[8];
  const float* trans = (const float*)d_in[9];
  int* out = (int*)d_out;

  // Workspace layout (bytes) — 23.67 MB total (<= R2's proven footprint):
  char* ws = (char*)d_ws;
  float* em = (float*)ws;                                        // 18,874,368
  unsigned char* bp = (unsigned char*)(ws + 18874368);           //  4,718,592
  float* Sfin = (float*)(ws + 23592960);                         //      2,304
  unsigned long long* Fws = (unsigned long long*)(ws + 23595264);//     65,536
  unsigned char* btags = (unsigned char*)(ws + 23660800);        //      8,256

  mlp_kernel<<<2048, 256, 0, stream>>>(x, W1, b1, W2, b2, W3, b3, em);
  vit_seq<<<16, 64, 0, stream>>>(em, trans, start_trans, bp, Sfin);
  vit_p4a<<<128, 64, 0, stream>>>(bp, Fws);
  vit_p4b<<<1, 64, 0, stream>>>(Sfin, end_trans, Fws, btags, out);
  vit_p4c<<<128, 64, 0, stream>>>(bp, btags, out);
}

// Round 6
// 2554.959 us; speedup vs baseline: 1.1174x; 1.1174x over previous
//
#include <hip/hip_runtime.h>
#include <hip/hip_bf16.h>

// Problem constants
#define B_ 64
#define T_ 8192
#define D_ 128
#define H1_ 128
#define H2_ 64
#define K_ 9
#define CS_ 64        // backtrace chunk size
#define NC_ 128       // number of backtrace chunks

// ---------------------------------------------------------------------------
// Kernel 1: fused MLP -> emissions (B*T, 9), fp32 OUTPUT with each layer's
// dot accumulated in fp64 (exact), rounded to fp32, bias added in fp32, relu
// in fp32 — correctly-rounded mimicry of the reference fp32 pipeline.
// R6 change: 512 threads = 8 waves, LDS = 160 KiB exactly -> 2 waves/SIMD
// (was 1), doubling latency hiding. Numerics bit-identical to R5 (passed).
// ---------------------------------------------------------------------------
__global__ __launch_bounds__(512) void mlp_kernel(
    const float* __restrict__ x, const float* __restrict__ W1, const float* __restrict__ b1,
    const float* __restrict__ W2, const float* __restrict__ b2,
    const float* __restrict__ W3, const float* __restrict__ b3,
    float* __restrict__ em) {
  __shared__ __align__(16) float sW1[128 * 128];   // 64 KB row-major [k][j]
  __shared__ __align__(16) float sW2[128 * 64];    // 32 KB row-major [k][j2]
  __shared__ __align__(16) float sX[8][1024];      // 32 KB: per-wave x [8][128]; reused as h2 [8][68]
  __shared__ __align__(16) float sH1[8][1024];     // 32 KB: per-wave h1 [8][128]
  // total 163840 B = 160 KiB (gfx950 per-WG max; 1 block/CU, 8 waves)

  const int tid = threadIdx.x;
  {
    float4* d1 = (float4*)sW1;
    const float4* g1 = (const float4*)W1;
    for (int i = tid; i < 128 * 128 / 4; i += 512) d1[i] = g1[i];
    float4* d2 = (float4*)sW2;
    const float4* g2 = (const float4*)W2;
    for (int i = tid; i < 128 * 64 / 4; i += 512) d2[i] = g2[i];
  }
  __syncthreads();

  const int wave = tid >> 6;
  const int lane = tid & 63;
  float* sx = sX[wave];
  float* sh1 = sH1[wave];
  const long blockTok0 = (long)blockIdx.x * 512;

  const float bj0 = b1[lane], bj1 = b1[64 + lane];
  const float b2v = b2[lane];
  const float b3A = b3[lane & 7];
  const float b3B = b3[8];

  for (int g = 0; g < 8; ++g) {
    const long tok0 = blockTok0 + g * 64 + wave * 8;  // 8 tokens for this wave
    const float4* xg = (const float4*)(x + tok0 * 128);
    float4* sx4 = (float4*)sx;
#pragma unroll
    for (int q = 0; q < 4; ++q) sx4[lane + q * 64] = xg[lane + q * 64];

    // ---- Layer 1: fp64 dot, fp32 round, fp32 +bias, fp32 relu ----
    double acc0[8], acc1[8];
#pragma unroll
    for (int t = 0; t < 8; ++t) { acc0[t] = 0.0; acc1[t] = 0.0; }
    for (int k = 0; k < 128; k += 4) {
      float4 xv[8];
#pragma unroll
      for (int t = 0; t < 8; ++t) xv[t] = *(const float4*)&sx[t * 128 + k];
#pragma unroll
      for (int kk = 0; kk < 4; ++kk) {
        const double w0 = (double)sW1[(k + kk) * 128 + lane];
        const double w1 = (double)sW1[(k + kk) * 128 + 64 + lane];
#pragma unroll
        for (int t = 0; t < 8; ++t) {
          const double xs = (double)((const float*)&xv[t])[kk];
          acc0[t] += xs * w0;
          acc1[t] += xs * w1;
        }
      }
    }
#pragma unroll
    for (int t = 0; t < 8; ++t) {
      sh1[t * 128 + lane] = fmaxf((float)acc0[t] + bj0, 0.f);
      sh1[t * 128 + 64 + lane] = fmaxf((float)acc1[t] + bj1, 0.f);
    }

    // ---- Layer 2: fp64 dot of fp32 h1, fp32 round, +bias, relu ----
    double acc2[8];
#pragma unroll
    for (int t = 0; t < 8; ++t) acc2[t] = 0.0;
    for (int k = 0; k < 128; k += 4) {
      float4 hv[8];
#pragma unroll
      for (int t = 0; t < 8; ++t) hv[t] = *(const float4*)&sh1[t * 128 + k];
#pragma unroll
      for (int kk = 0; kk < 4; ++kk) {
        const double w = (double)sW2[(k + kk) * 64 + lane];
#pragma unroll
        for (int t = 0; t < 8; ++t) acc2[t] += (double)((const float*)&hv[t])[kk] * w;
      }
    }
    float* sh2 = sx;  // x tile dead; reuse. Row stride 68 floats.
#pragma unroll
    for (int t = 0; t < 8; ++t) sh2[t * 68 + lane] = fmaxf((float)acc2[t] + b2v, 0.f);

    // ---- Layer 3: fp64 dot of fp32 h2, fp32 round, fp32 +bias ----
    {
      const int tokA = lane >> 3, j3 = lane & 7;
      double acc3 = 0.0;
      for (int k = 0; k < 64; ++k) acc3 += (double)sh2[tokA * 68 + k] * (double)W3[k * 9 + j3];
      em[(tok0 + tokA) * 9 + j3] = (float)acc3 + b3A;
    }
    {
      const int tokB = lane & 7;
      double acc4 = 0.0;
      for (int k = 0; k < 64; ++k) acc4 += (double)sh2[tokB * 68 + k] * (double)W3[k * 9 + 8];
      if (lane < 8) em[(tok0 + tokB) * 9 + 8] = (float)acc4 + b3B;
    }
  }
}

// ---------------------------------------------------------------------------
// Viterbi forward, EXACT sequential fp32 recursion. R6 rewrite of R5's VSTEP,
// bit-identical outputs (proof in comments), fewer ops + shorter chain:
//  - a_i = fl(s_i + tr_ij); ref cand c_i = fl(a_i + e_j).
//  - max_i c_i == fl(max_i a_i + e_j)   [rounding is monotone => max commutes]
//    so the new score sn needs ONE +e after the max tree, and the cand max
//    needs no second tree.
//  - backpointer: first i with c_i == sn, computed via 9 independent
//    select-bits + or-tree + clz (was a 16-op dependent chain).
//  - raw ds_bpermute with 9 hoisted byte-addresses (was width-16 __shfl).
//  - pointer-bump addressing, constant imm offsets (no per-step 64-bit mul).
//  - no exec-mask churn: lanes 9..15 clamp to j=8, compute identical values,
//    and their bp byte store duplicates lane 8's (same address, same value —
//    benign). Layout: 4 batches/wave in 16-lane groups, lane%16 = tag j.
// ---------------------------------------------------------------------------
#define VSTEP2(EV, BOFF)                                                      \
  {                                                                           \
    const float e_ = (EV);                                                    \
    const int si_ = __float_as_int(s);                                        \
    const float s0_ = __int_as_float(__builtin_amdgcn_ds_bpermute(ba0_, si_));\
    const float s1_ = __int_as_float(__builtin_amdgcn_ds_bpermute(ba1_, si_));\
    const float s2_ = __int_as_float(__builtin_amdgcn_ds_bpermute(ba2_, si_));\
    const float s3_ = __int_as_float(__builtin_amdgcn_ds_bpermute(ba3_, si_));\
    const float s4_ = __int_as_float(__builtin_amdgcn_ds_bpermute(ba4_, si_));\
    const float s5_ = __int_as_float(__builtin_amdgcn_ds_bpermute(ba5_, si_));\
    const float s6_ = __int_as_float(__builtin_amdgcn_ds_bpermute(ba6_, si_));\
    const float s7_ = __int_as_float(__builtin_amdgcn_ds_bpermute(ba7_, si_));\
    const float s8_ = __int_as_float(__builtin_amdgcn_ds_bpermute(ba8_, si_));\
    const float a0_ = s0_ + tr[0];                                            \
    const float a1_ = s1_ + tr[1];                                            \
    const float a2_ = s2_ + tr[2];                                            \
    const float a3_ = s3_ + tr[3];                                            \
    const float a4_ = s4_ + tr[4];                                            \
    const float a5_ = s5_ + tr[5];                                            \
    const float a6_ = s6_ + tr[6];                                            \
    const float a7_ = s7_ + tr[7];                                            \
    float mx_ = fmaxf(fmaxf(fmaxf(a0_, a1_), fmaxf(a2_, a3_)),                \
                      fmaxf(fmaxf(a4_, a5_), fmaxf(a6_, a7_)));               \
    const float a8_ = s8_ + tr[8];                                            \
    mx_ = fmaxf(mx_, a8_);                                                    \
    const float sn_ = mx_ + e_;                                               \
    unsigned bits_ = 0u;                                                      \
    bits_ |= ((a0_ + e_) == sn_) ? 256u : 0u;                                 \
    bits_ |= ((a1_ + e_) == sn_) ? 128u : 0u;                                 \
    bits_ |= ((a2_ + e_) == sn_) ? 64u : 0u;                                  \
    bits_ |= ((a3_ + e_) == sn_) ? 32u : 0u;                                  \
    bits_ |= ((a4_ + e_) == sn_) ? 16u : 0u;                                  \
    bits_ |= ((a5_ + e_) == sn_) ? 8u : 0u;                                   \
    bits_ |= ((a6_ + e_) == sn_) ? 4u : 0u;                                   \
    bits_ |= ((a7_ + e_) == sn_) ? 2u : 0u;                                   \
    bits_ |= ((a8_ + e_) == sn_) ? 1u : 0u;                                   \
    bpp[BOFF] = (unsigned char)(__clz((int)bits_) - 23);                      \
    s = sn_;                                                                  \
  }

__global__ __launch_bounds__(64) void vit_seq(
    const float* __restrict__ em, const float* __restrict__ trans,
    const float* __restrict__ start_trans,
    unsigned char* __restrict__ bp, float* __restrict__ Sfin) {
  const int lane = threadIdx.x;
  const int j = lane & 15;
  const int jj = (j < 9) ? j : 8;  // lanes 9..15 mirror j=8 (benign duplicates)
  const int b = blockIdx.x * 4 + (lane >> 4);

  // hoisted bpermute byte-addresses: group base lane * 4 + i*4
  const int gb4_ = (lane & 48) << 2;
  const int ba0_ = gb4_ + 0,  ba1_ = gb4_ + 4,  ba2_ = gb4_ + 8;
  const int ba3_ = gb4_ + 12, ba4_ = gb4_ + 16, ba5_ = gb4_ + 20;
  const int ba6_ = gb4_ + 24, ba7_ = gb4_ + 28, ba8_ = gb4_ + 32;

  float tr[9];
#pragma unroll
  for (int i = 0; i < 9; ++i) tr[i] = trans[i * 9 + jj];

  const float* eb = em + ((long)b * T_) * 9 + jj;
  unsigned char* bpp = bp + ((long)b * T_) * 9 + jj + 9;  // step-1 slot

  float s = start_trans[jj] + eb[0];  // score0, exact reference association

  const float* ep = eb + 9;  // step-1 emission
  float ea[8], en[8];
#pragma unroll
  for (int u = 0; u < 8; ++u) ea[u] = ep[u * 9];
  ep += 72;  // first prefetch target: step 9

  // 1023 groups of 8: steps 1..8184. Last prefetch touches "step 8192" which
  // for b=63 reads (allocated) bp workspace — value never used.
  for (int it = 0; it < 1023; ++it) {
#pragma unroll
    for (int u = 0; u < 8; ++u) en[u] = ep[u * 9];
#pragma unroll
    for (int u = 0; u < 8; ++u) VSTEP2(ea[u], u * 9);
#pragma unroll
    for (int u = 0; u < 8; ++u) ea[u] = en[u];
    ep += 72;
    bpp += 72;
  }
  // tail: steps 8185..8191
#pragma unroll
  for (int u = 0; u < 7; ++u) VSTEP2(ea[u], u * 9);

  if (j < 9) Sfin[b * 9 + j] = s;
}

// ---------------------------------------------------------------------------
// Backtrace a: per-chunk composed backpointer map F_c (end-tag -> start-tag),
// 9 nibbles packed in u64. Pure integer => chunking is exact.
// ---------------------------------------------------------------------------
__global__ void vit_p4a(const unsigned char* __restrict__ bp,
                        unsigned long long* __restrict__ Fws) {
  const int task = blockIdx.x * blockDim.x + threadIdx.x;
  if (task >= B_ * NC_) return;
  const int b = task >> 7, c = task & 127;
  int m[9];
#pragma unroll
  for (int q = 0; q < 9; ++q) m[q] = q;
  const int t0 = c * CS_ + 1;
  const int t1 = min(t0 + CS_, T_);
  const unsigned char* bpb = bp + ((long)b * T_) * 9;
  for (int t = t1 - 1; t >= t0; --t) {
#pragma unroll
    for (int q = 0; q < 9; ++q) m[q] = bpb[(long)t * 9 + m[q]];
  }
  unsigned long long f = 0ull;
#pragma unroll
  for (int q = 0; q < 9; ++q) f |= ((unsigned long long)m[q]) << (4 * q);
  Fws[task] = f;
}

// ---------------------------------------------------------------------------
// Backtrace b: final argmax (first-max, ascending strict >) + scan of F maps
// -> chunk-boundary tags. One block, 64 threads (lane = batch).
// ---------------------------------------------------------------------------
__global__ void vit_p4b(const float* __restrict__ Sfin, const float* __restrict__ end_trans,
                        const unsigned long long* __restrict__ Fws,
                        unsigned char* __restrict__ btags, int* __restrict__ out) {
  __shared__ unsigned long long F[B_ * NC_];
  for (int idx = threadIdx.x; idx < B_ * NC_; idx += 64) F[idx] = Fws[idx];
  __syncthreads();
  const int b = threadIdx.x;
  if (b >= B_) return;
  const float* sf = Sfin + b * 9;
  float best = sf[0] + end_trans[0];
  int bi = 0;
#pragma unroll
  for (int q = 1; q < 9; ++q) {
    const float v = sf[q] + end_trans[q];
    if (v > best) { best = v; bi = q; }
  }
  out[b * T_ + T_ - 1] = bi;
  int tag = bi;
  btags[b * (NC_ + 1) + NC_] = (unsigned char)tag;
  for (int c = NC_ - 1; c >= 0; --c) {
    const unsigned long long f = F[b * NC_ + c];
    tag = (int)((f >> (4 * tag)) & 15ull);
    btags[b * (NC_ + 1) + c] = (unsigned char)tag;
  }
}

// ---------------------------------------------------------------------------
// Backtrace c: re-walk each chunk from its known end-boundary tag, writing
// output tags. Pure integer byte-lookup chain.
// ---------------------------------------------------------------------------
__global__ void vit_p4c(const unsigned char* __restrict__ bp,
                        const unsigned char* __restrict__ btags, int* __restrict__ out) {
  const int task = blockIdx.x * blockDim.x + threadIdx.x;
  if (task >= B_ * NC_) return;
  const int b = task >> 7, c = task & 127;
  int tag = btags[b * (NC_ + 1) + c + 1];
  const int t0 = c * CS_ + 1;
  const int t1 = min(t0 + CS_, T_);
  const unsigned char* bpb = bp + ((long)b * T_) * 9;
  int* ob = out + b * T_;
  for (int t = t1 - 1; t >= t0; --t) {
    tag = bpb[(long)t * 9 + tag];
    ob[t - 1] = tag;
  }
}

// ---------------------------------------------------------------------------
extern "C" void kernel_launch(void* const* d_in, const int* in_sizes, int n_in,
                              void* d_out, int out_size, void* d_ws, size_t ws_size,
                              hipStream_t stream) {
  (void)in_sizes; (void)n_in; (void)out_size; (void)ws_size;
  const float* x = (const float*)d_in[0];
  const float* W1 = (const float*)d_in[1];
  const float* b1 = (const float*)d_in[2];
  const float* W2 = (const float*)d_in[3];
  const float* b2 = (const float*)d_in[4];
  const float* W3 = (const float*)d_in[5];
  const float* b3 = (const float*)d_in[6];
  const float* start_trans = (const float*)d_in[7];
  const float* end_trans = (const float*)d_in[8];
  const float* trans = (const float*)d_in[9];
  int* out = (int*)d_out;

  // Workspace layout (bytes) — 23.67 MB total (R5-proven footprint):
  char* ws = (char*)d_ws;
  float* em = (float*)ws;                                        // 18,874,368
  unsigned char* bp = (unsigned char*)(ws + 18874368);           //  4,718,592
  float* Sfin = (float*)(ws + 23592960);                         //      2,304
  unsigned long long* Fws = (unsigned long long*)(ws + 23595264);//     65,536
  unsigned char* btags = (unsigned char*)(ws + 23660800);        //      8,256

  mlp_kernel<<<1024, 512, 0, stream>>>(x, W1, b1, W2, b2, W3, b3, em);
  vit_seq<<<16, 64, 0, stream>>>(em, trans, start_trans, bp, Sfin);
  vit_p4a<<<128, 64, 0, stream>>>(bp, Fws);
  vit_p4b<<<1, 64, 0, stream>>>(Sfin, end_trans, Fws, btags, out);
  vit_p4c<<<128, 64, 0, stream>>>(bp, btags, out);
}

// Round 7
// 1723.960 us; speedup vs baseline: 1.6560x; 1.4820x over previous
//
#include <hip/hip_runtime.h>
#include <hip/hip_bf16.h>

// Problem constants
#define B_ 64
#define T_ 8192
#define D_ 128
#define H1_ 128
#define H2_ 64
#define K_ 9
#define CS_ 64        // scan snapshot / backtrace chunk size
#define NC_ 128       // number of chunks

// ---------------------------------------------------------------------------
// Kernel 1: fused MLP -> emissions (B*T, 9). Numerics IDENTICAL to R6 (passed,
// absmax 0): each layer = fp64 ascending-k dot (exact products, sequential
// fp64 FMA), round to fp32, +bias fp32, relu fp32.
// R7 change (perf only): conversions hoisted out of MAC loops. x staged as
// double cooperatively (16 cvt/lane, was 1024); h1/h2 stored as
// double(fp32-rounded value) directly from the accumulator (0 cvt, was 1024).
// One 8KB/wave double scratch reused x_d -> h1_d -> h2_d (wave-private,
// DS ops in-order per wave => no barriers needed between phases).
// LDS: W1 fp32 64K + W2 fp32 32K + 8 waves x 8K double = 160 KiB exactly.
// ---------------------------------------------------------------------------
__global__ __launch_bounds__(512) void mlp_kernel(
    const float* __restrict__ x, const float* __restrict__ W1, const float* __restrict__ b1,
    const float* __restrict__ W2, const float* __restrict__ b2,
    const float* __restrict__ W3, const float* __restrict__ b3,
    float* __restrict__ em) {
  __shared__ __align__(16) float sW1[128 * 128];   // 64 KB row-major [k][j]
  __shared__ __align__(16) float sW2[128 * 64];    // 32 KB row-major [k][j2]
  __shared__ __align__(16) double sD[8][1024];     // 64 KB: per-wave x_d/h1_d/h2_d

  const int tid = threadIdx.x;
  {
    float4* d1 = (float4*)sW1;
    const float4* g1 = (const float4*)W1;
    for (int i = tid; i < 128 * 128 / 4; i += 512) d1[i] = g1[i];
    float4* d2 = (float4*)sW2;
    const float4* g2 = (const float4*)W2;
    for (int i = tid; i < 128 * 64 / 4; i += 512) d2[i] = g2[i];
  }
  __syncthreads();

  const int wave = tid >> 6;
  const int lane = tid & 63;
  double* sd = sD[wave];
  const long blockTok0 = (long)blockIdx.x * 512;

  const float bj0 = b1[lane], bj1 = b1[64 + lane];
  const float b2v = b2[lane];
  const float b3A = b3[lane & 7];
  const float b3B = b3[8];

  for (int g = 0; g < 8; ++g) {
    const long tok0 = blockTok0 + g * 64 + wave * 8;  // 8 tokens for this wave

    // stage x tile as double: 1024 elts, 16 per lane (4 float4 -> 16 cvt)
    const float4* xg = (const float4*)(x + tok0 * 128);
#pragma unroll
    for (int q = 0; q < 4; ++q) {
      const float4 v = xg[lane + q * 64];
      const int base = (lane + q * 64) * 4;
      sd[base + 0] = (double)v.x;
      sd[base + 1] = (double)v.y;
      sd[base + 2] = (double)v.z;
      sd[base + 3] = (double)v.w;
    }

    // ---- Layer 1: fp64 dot (ascending k), fp32 round, +bias, relu ----
    double acc0[8], acc1[8];
#pragma unroll
    for (int t = 0; t < 8; ++t) { acc0[t] = 0.0; acc1[t] = 0.0; }
    for (int k = 0; k < 128; k += 2) {
      double2 xv[8];
#pragma unroll
      for (int t = 0; t < 8; ++t) xv[t] = *(const double2*)&sd[t * 128 + k];
      const double w00 = (double)sW1[k * 128 + lane];
      const double w01 = (double)sW1[k * 128 + 64 + lane];
      const double w10 = (double)sW1[(k + 1) * 128 + lane];
      const double w11 = (double)sW1[(k + 1) * 128 + 64 + lane];
#pragma unroll
      for (int t = 0; t < 8; ++t) {
        acc0[t] += xv[t].x * w00;
        acc1[t] += xv[t].x * w01;
        acc0[t] += xv[t].y * w10;
        acc1[t] += xv[t].y * w11;
      }
    }
    // all x_d reads complete (in-order wave) -> overwrite with h1_d
#pragma unroll
    for (int t = 0; t < 8; ++t) {
      sd[t * 128 + lane] = (double)fmaxf((float)acc0[t] + bj0, 0.f);
      sd[t * 128 + 64 + lane] = (double)fmaxf((float)acc1[t] + bj1, 0.f);
    }

    // ---- Layer 2: fp64 dot of h1 (fp32 values), fp32 round, +bias, relu ----
    double acc2[8];
#pragma unroll
    for (int t = 0; t < 8; ++t) acc2[t] = 0.0;
    for (int k = 0; k < 128; k += 2) {
      double2 hv[8];
#pragma unroll
      for (int t = 0; t < 8; ++t) hv[t] = *(const double2*)&sd[t * 128 + k];
      const double w0 = (double)sW2[k * 64 + lane];
      const double w1 = (double)sW2[(k + 1) * 64 + lane];
#pragma unroll
      for (int t = 0; t < 8; ++t) {
        acc2[t] += hv[t].x * w0;
        acc2[t] += hv[t].y * w1;
      }
    }
    // h1_d reads complete -> overwrite with h2_d (stride 66 doubles)
#pragma unroll
    for (int t = 0; t < 8; ++t) sd[t * 66 + lane] = (double)fmaxf((float)acc2[t] + b2v, 0.f);

    // ---- Layer 3: fp64 dot of h2, fp32 round, fp32 +bias ----
    {
      const int tokA = lane >> 3, j3 = lane & 7;
      double acc3 = 0.0;
      for (int k = 0; k < 64; ++k) acc3 += sd[tokA * 66 + k] * (double)W3[k * 9 + j3];
      em[(tok0 + tokA) * 9 + j3] = (float)acc3 + b3A;
    }
    {
      const int tokB = lane & 7;
      double acc4 = 0.0;
      for (int k = 0; k < 64; ++k) acc4 += sd[tokB * 66 + k] * (double)W3[k * 9 + 8];
      if (lane < 8) em[(tok0 + tokB) * 9 + 8] = (float)acc4 + b3B;
    }
  }
}

// ---------------------------------------------------------------------------
// Viterbi scan, bit-exact fp32 recursion via DPP row rotations (R7).
// Semantics identical to R6's proven form: a_i = fl(s_i + tr_ij);
// sn = fl(max_i a_i + e_j)  [max commutes with monotone rounding];
// backpointer (phase B only) = first i with fl(a_i + e) == sn.
// Cross-lane s_i gather: 15 v_mov_b32_dpp row_ror:k (VALU latency, replaces
// 9 ds_bpermute LDS round-trips on the recurrence chain). The lane->source
// mapping of each rotation is DISCOVERED at runtime (rotate the lane index),
// so correctness is independent of ror direction convention. Sources with
// index >8 (idle lanes 9..15) get trk=-inf -> value-filtered; lanes 9..15
// therefore compute exactly lane 8's values (benign duplicate stores).
// Layout: 4 batches/wave in 16-lane rows, lane%16 = tag j.
// ---------------------------------------------------------------------------
#define NEGINF_F (-__builtin_huge_valf())

#define DISCK(K)                                                              \
  {                                                                           \
    const int ik_ = __builtin_amdgcn_mov_dpp(j, 0x120 + K, 0xF, 0xF, true);   \
    const bool v_ = (ik_ <= 8);                                               \
    trk[K] = v_ ? trans[ik_ * 9 + jj] : NEGINF_F;                             \
    ibit[K] = v_ ? (1u << (8 - ik_)) : 0u;                                    \
  }

#define CANDK(K)                                                              \
  const float c##K##_ =                                                       \
      __int_as_float(__builtin_amdgcn_mov_dpp(si_, 0x120 + K, 0xF, 0xF, true)) + trk[K];

#define VCANDS                                                                \
  const int si_ = __float_as_int(s);                                          \
  const float c0_ = s + trk[0];                                               \
  CANDK(1) CANDK(2) CANDK(3) CANDK(4) CANDK(5) CANDK(6) CANDK(7) CANDK(8)     \
  CANDK(9) CANDK(10) CANDK(11) CANDK(12) CANDK(13) CANDK(14) CANDK(15)        \
  const float m0_ = fmaxf(fmaxf(c0_, c1_), fmaxf(c2_, c3_));                  \
  const float m1_ = fmaxf(fmaxf(c4_, c5_), fmaxf(c6_, c7_));                  \
  const float m2_ = fmaxf(fmaxf(c8_, c9_), fmaxf(c10_, c11_));                \
  const float m3_ = fmaxf(fmaxf(c12_, c13_), fmaxf(c14_, c15_));              \
  const float mx_ = fmaxf(fmaxf(m0_, m1_), fmaxf(m2_, m3_));

#define VSCAN(EV)                                                             \
  {                                                                           \
    const float e_ = (EV);                                                    \
    VCANDS                                                                    \
    s = mx_ + e_;                                                             \
  }

#define VBP(EV)                                                               \
  {                                                                           \
    const float e_ = (EV);                                                    \
    VCANDS                                                                    \
    const float sn_ = mx_ + e_;                                               \
    unsigned bits_ = 0u;                                                      \
    bits_ |= ((c0_ + e_) == sn_) ? ibit[0] : 0u;                              \
    bits_ |= ((c1_ + e_) == sn_) ? ibit[1] : 0u;                              \
    bits_ |= ((c2_ + e_) == sn_) ? ibit[2] : 0u;                              \
    bits_ |= ((c3_ + e_) == sn_) ? ibit[3] : 0u;                              \
    bits_ |= ((c4_ + e_) == sn_) ? ibit[4] : 0u;                              \
    bits_ |= ((c5_ + e_) == sn_) ? ibit[5] : 0u;                              \
    bits_ |= ((c6_ + e_) == sn_) ? ibit[6] : 0u;                              \
    bits_ |= ((c7_ + e_) == sn_) ? ibit[7] : 0u;                              \
    bits_ |= ((c8_ + e_) == sn_) ? ibit[8] : 0u;                              \
    bits_ |= ((c9_ + e_) == sn_) ? ibit[9] : 0u;                              \
    bits_ |= ((c10_ + e_) == sn_) ? ibit[10] : 0u;                            \
    bits_ |= ((c11_ + e_) == sn_) ? ibit[11] : 0u;                            \
    bits_ |= ((c12_ + e_) == sn_) ? ibit[12] : 0u;                            \
    bits_ |= ((c13_ + e_) == sn_) ? ibit[13] : 0u;                            \
    bits_ |= ((c14_ + e_) == sn_) ? ibit[14] : 0u;                            \
    bits_ |= ((c15_ + e_) == sn_) ? ibit[15] : 0u;                            \
    bpp[0] = (unsigned char)(__clz((int)bits_) - 23);                         \
    s = sn_;                                                                  \
  }

// Phase A: sequential scan, snapshots every CS_ steps, no backpointers.
__global__ __launch_bounds__(64) void vit_scan(
    const float* __restrict__ em, const float* __restrict__ trans,
    const float* __restrict__ start_trans,
    float* __restrict__ Ssnap, float* __restrict__ Sfin) {
  const int lane = threadIdx.x;
  const int j = lane & 15;
  const int jj = (j < 9) ? j : 8;
  const int b = blockIdx.x * 4 + (lane >> 4);

  float trk[16];
  unsigned ibit[16];
  {  // k = 0: source is own lane
    const bool v_ = (j <= 8);
    trk[0] = v_ ? trans[jj * 9 + jj] : NEGINF_F;
    ibit[0] = v_ ? (1u << (8 - jj)) : 0u;
  }
  DISCK(1) DISCK(2) DISCK(3) DISCK(4) DISCK(5) DISCK(6) DISCK(7) DISCK(8)
  DISCK(9) DISCK(10) DISCK(11) DISCK(12) DISCK(13) DISCK(14) DISCK(15)

  const float* eb = em + ((long)b * T_) * 9 + jj;
  float s = start_trans[jj] + eb[0];  // score0, exact reference association

  const float* ep = eb + 9;
  float ea[8], en[8];
#pragma unroll
  for (int u = 0; u < 8; ++u) ea[u] = ep[u * 9];
  ep += 72;

  float* snp = Ssnap + ((long)b * NC_) * 9 + jj;

  for (int it = 0; it < 1023; ++it) {
    if ((it & 7) == 0) { *snp = s; snp += 9; }  // snapshot c = it/8 (s_{c*64})
#pragma unroll
    for (int u = 0; u < 8; ++u) en[u] = ep[u * 9];
#pragma unroll
    for (int u = 0; u < 8; ++u) VSCAN(ea[u]);
#pragma unroll
    for (int u = 0; u < 8; ++u) ea[u] = en[u];
    ep += 72;
  }
#pragma unroll
  for (int u = 0; u < 7; ++u) VSCAN(ea[u]);  // steps 8185..8191

  Sfin[b * 9 + jj] = s;  // lanes 9..15 duplicate lane 8's value: benign
}

// Phase B: parallel per-chunk replay from exact snapshots, emitting
// backpointers. Same instruction sequence as phase A => bit-identical.
__global__ __launch_bounds__(64) void vit_bp(
    const float* __restrict__ em, const float* __restrict__ trans,
    const float* __restrict__ Ssnap, unsigned char* __restrict__ bp) {
  const int lane = threadIdx.x;
  const int j = lane & 15;
  const int jj = (j < 9) ? j : 8;
  const int task = blockIdx.x * 4 + (lane >> 4);
  const int b = task >> 7, c = task & 127;

  float trk[16];
  unsigned ibit[16];
  {
    const bool v_ = (j <= 8);
    trk[0] = v_ ? trans[jj * 9 + jj] : NEGINF_F;
    ibit[0] = v_ ? (1u << (8 - jj)) : 0u;
  }
  DISCK(1) DISCK(2) DISCK(3) DISCK(4) DISCK(5) DISCK(6) DISCK(7) DISCK(8)
  DISCK(9) DISCK(10) DISCK(11) DISCK(12) DISCK(13) DISCK(14) DISCK(15)

  float s = Ssnap[((long)b * NC_ + c) * 9 + jj];

  const int t0 = c * CS_ + 1;
  const int t1 = min(t0 + CS_, T_);
  const float* ebp = em + (((long)b * T_) + t0) * 9 + jj;
  unsigned char* bpp = bp + (((long)b * T_) + t0) * 9 + jj;
  for (int t = t0; t < t1; ++t) {
    const float e0_ = ebp[0];
    VBP(e0_);
    ebp += 9;
    bpp += 9;
  }
}

// ---------------------------------------------------------------------------
// Backtrace a: per-chunk composed backpointer map F_c (end-tag -> start-tag),
// 9 nibbles packed in u64. Pure integer => chunking is exact.
// ---------------------------------------------------------------------------
__global__ void vit_p4a(const unsigned char* __restrict__ bp,
                        unsigned long long* __restrict__ Fws) {
  const int task = blockIdx.x * blockDim.x + threadIdx.x;
  if (task >= B_ * NC_) return;
  const int b = task >> 7, c = task & 127;
  int m[9];
#pragma unroll
  for (int q = 0; q < 9; ++q) m[q] = q;
  const int t0 = c * CS_ + 1;
  const int t1 = min(t0 + CS_, T_);
  const unsigned char* bpb = bp + ((long)b * T_) * 9;
  for (int t = t1 - 1; t >= t0; --t) {
#pragma unroll
    for (int q = 0; q < 9; ++q) m[q] = bpb[(long)t * 9 + m[q]];
  }
  unsigned long long f = 0ull;
#pragma unroll
  for (int q = 0; q < 9; ++q) f |= ((unsigned long long)m[q]) << (4 * q);
  Fws[task] = f;
}

// ---------------------------------------------------------------------------
// Backtrace b: final argmax (first-max, ascending strict >) + scan of F maps
// -> chunk-boundary tags. One block, 64 threads (lane = batch).
// ---------------------------------------------------------------------------
__global__ void vit_p4b(const float* __restrict__ Sfin, const float* __restrict__ end_trans,
                        const unsigned long long* __restrict__ Fws,
                        unsigned char* __restrict__ btags, int* __restrict__ out) {
  __shared__ unsigned long long F[B_ * NC_];
  for (int idx = threadIdx.x; idx < B_ * NC_; idx += 64) F[idx] = Fws[idx];
  __syncthreads();
  const int b = threadIdx.x;
  if (b >= B_) return;
  const float* sf = Sfin + b * 9;
  float best = sf[0] + end_trans[0];
  int bi = 0;
#pragma unroll
  for (int q = 1; q < 9; ++q) {
    const float v = sf[q] + end_trans[q];
    if (v > best) { best = v; bi = q; }
  }
  out[b * T_ + T_ - 1] = bi;
  int tag = bi;
  btags[b * (NC_ + 1) + NC_] = (unsigned char)tag;
  for (int c = NC_ - 1; c >= 0; --c) {
    const unsigned long long f = F[b * NC_ + c];
    tag = (int)((f >> (4 * tag)) & 15ull);
    btags[b * (NC_ + 1) + c] = (unsigned char)tag;
  }
}

// ---------------------------------------------------------------------------
// Backtrace c: re-walk each chunk from its known end-boundary tag, writing
// output tags. Pure integer byte-lookup chain.
// ---------------------------------------------------------------------------
__global__ void vit_p4c(const unsigned char* __restrict__ bp,
                        const unsigned char* __restrict__ btags, int* __restrict__ out) {
  const int task = blockIdx.x * blockDim.x + threadIdx.x;
  if (task >= B_ * NC_) return;
  const int b = task >> 7, c = task & 127;
  int tag = btags[b * (NC_ + 1) + c + 1];
  const int t0 = c * CS_ + 1;
  const int t1 = min(t0 + CS_, T_);
  const unsigned char* bpb = bp + ((long)b * T_) * 9;
  int* ob = out + b * T_;
  for (int t = t1 - 1; t >= t0; --t) {
    tag = bpb[(long)t * 9 + tag];
    ob[t - 1] = tag;
  }
}

// ---------------------------------------------------------------------------
extern "C" void kernel_launch(void* const* d_in, const int* in_sizes, int n_in,
                              void* d_out, int out_size, void* d_ws, size_t ws_size,
                              hipStream_t stream) {
  (void)in_sizes; (void)n_in; (void)out_size; (void)ws_size;
  const float* x = (const float*)d_in[0];
  const float* W1 = (const float*)d_in[1];
  const float* b1 = (const float*)d_in[2];
  const float* W2 = (const float*)d_in[3];
  const float* b2 = (const float*)d_in[4];
  const float* W3 = (const float*)d_in[5];
  const float* b3 = (const float*)d_in[6];
  const float* start_trans = (const float*)d_in[7];
  const float* end_trans = (const float*)d_in[8];
  const float* trans = (const float*)d_in[9];
  int* out = (int*)d_out;

  // Workspace layout (bytes) — ~24.0 MB (<= R4's proven 43.7 MB usage):
  char* ws = (char*)d_ws;
  float* em = (float*)ws;                                        // 18,874,368
  unsigned char* bp = (unsigned char*)(ws + 18874368);           //  4,718,592
  float* Ssnap = (float*)(ws + 23592960);                        //    294,912
  float* Sfin = (float*)(ws + 23887872);                         //      2,304
  unsigned long long* Fws = (unsigned long long*)(ws + 23890176);//     65,536
  unsigned char* btags = (unsigned char*)(ws + 23955712);        //      8,256

  mlp_kernel<<<1024, 512, 0, stream>>>(x, W1, b1, W2, b2, W3, b3, em);
  vit_scan<<<16, 64, 0, stream>>>(em, trans, start_trans, Ssnap, Sfin);
  vit_bp<<<2048, 64, 0, stream>>>(em, trans, Ssnap, bp);
  vit_p4a<<<128, 64, 0, stream>>>(bp, Fws);
  vit_p4b<<<1, 64, 0, stream>>>(Sfin, end_trans, Fws, btags, out);
  vit_p4c<<<128, 64, 0, stream>>>(bp, btags, out);
}